// Round 13
// baseline (102.813 us; speedup 1.0000x reference)
//
#include <hip/hip_runtime.h>
#include <hip/hip_bf16.h>

// Problem constants: B=2, C=128, H=W=D=24, S=13824, NH=4, hd=32, pooled SKV=1728, G=8
#define SB 2
#define SC 128
#define SS 13824
#define SNH 4
#define SHD 32
#define SKV 1728
#define GN_N 221184.0f        // elems per (b,g) = 16*13824
#define QSCALE 0.25504771249f // (1/sqrt(32)) * log2(e)

typedef unsigned int uint;
typedef unsigned short ushort;
typedef __bf16 bf16x8 __attribute__((ext_vector_type(8)));
typedef float f32x16 __attribute__((ext_vector_type(16)));

__device__ inline ushort f2bf(float v){
  __hip_bfloat16 h = __float2bfloat16(v);
  return *reinterpret_cast<ushort*>(&h);
}
__device__ inline float bf2f(ushort u){
  union { ushort s[2]; float f; } x; x.s[0] = 0; x.s[1] = u; return x.f;
}
__device__ inline uint pk2(float a, float b){
  __hip_bfloat162 h = __float22bfloat162_rn(make_float2(a, b));
  return *reinterpret_cast<uint*>(&h);
}
__device__ inline bf16x8 ldg8(const ushort* p){
  union { uint4 q; bf16x8 b; } u;
  u.q = *reinterpret_cast<const uint4*>(p);
  return u.b;
}
__device__ inline f32x16 mfma32(bf16x8 a, bf16x8 b, f32x16 c){
  return __builtin_amdgcn_mfma_f32_32x32x16_bf16(a, b, c, 0, 0, 0);
}
// C/D layout of 32x32 MFMA: col = lane&31, row = (r&3) + 8*((r>>2)&1) + 4*(lane>>5) + 16*(r>>3)
__device__ inline int rowmap(int r, int hl){
  return (r & 3) + 8 * ((r >> 2) & 1) + 4 * hl + 16 * (r >> 3);
}
// RAW v_exp_f32: guaranteed single TRANS-pipe instruction.
// Safe domain here: |scores| < ~40, so no denormal/inf handling needed.
__device__ inline float vexp2(float x){
  float r;
  asm("v_exp_f32 %0, %1" : "=v"(r) : "v"(x));
  return r;
}

// ---------------- K1a: per-channel sums for GroupNorm stats ----------------
__global__ __launch_bounds__(256) void k_stats(const float* __restrict__ x, float* __restrict__ chsums){
  int bid = blockIdx.x;            // 256 blocks = (b, c)
  int b = bid >> 7, c = bid & 127;
  const float4* p = reinterpret_cast<const float4*>(x + (size_t)(b * 128 + c) * SS);
  float s = 0.f, q = 0.f;
  for (int i = threadIdx.x; i < SS / 4; i += 256){
    float4 v = p[i];
    s += v.x + v.y + v.z + v.w;
    q += v.x * v.x + v.y * v.y + v.z * v.z + v.w * v.w;
  }
  for (int off = 32; off; off >>= 1){ s += __shfl_down(s, off, 64); q += __shfl_down(q, off, 64); }
  __shared__ float ls[4][2];
  int w = threadIdx.x >> 6, lane = threadIdx.x & 63;
  if (lane == 0){ ls[w][0] = s; ls[w][1] = q; }
  __syncthreads();
  if (threadIdx.x == 0){
    float S = ls[0][0] + ls[1][0] + ls[2][0] + ls[3][0];
    float Q = ls[0][1] + ls[1][1] + ls[2][1] + ls[3][1];
    chsums[(b * 128 + c) * 2] = S;
    chsums[(b * 128 + c) * 2 + 1] = Q;
  }
}

// ---------------- K1b: fold GN into qkv weights; convert proj_w ----------------
__global__ __launch_bounds__(256) void k_params(const float* __restrict__ chsums,
                                                const float* __restrict__ gn_w, const float* __restrict__ gn_b,
                                                const float* __restrict__ qkv_w, const float* __restrict__ qkv_b,
                                                const float* __restrict__ proj_w,
                                                ushort* __restrict__ Wp, float* __restrict__ biasP,
                                                ushort* __restrict__ pw){
  int tid = blockIdx.x * 256 + threadIdx.x;
  if (tid < 768){
    int b = tid / 384, o = tid % 384;
    float mul = (o < 128) ? QSCALE : 1.0f; // fold softmax scale*log2e into q
    ushort* wrow = Wp + (size_t)(b * 384 + o) * 128;
    float acc = 0.f;
    for (int g = 0; g < 8; ++g){
      float S = 0.f, Q = 0.f;
      for (int ch = g * 16; ch < g * 16 + 16; ++ch){
        S += chsums[(b * 128 + ch) * 2];
        Q += chsums[(b * 128 + ch) * 2 + 1];
      }
      float mu = S * (1.0f / GN_N);
      float var = Q * (1.0f / GN_N) - mu * mu;
      float rs = rsqrtf(var + 1e-5f);
      for (int ci = 0; ci < 16; ++ci){
        int c = g * 16 + ci;
        float a = gn_w[c] * rs;
        float be = gn_b[c] - mu * a;
        float wv = qkv_w[o * 128 + c];
        acc += wv * be;
        wrow[c] = f2bf(wv * a * mul);
      }
    }
    biasP[b * 384 + o] = (qkv_b[o] + acc) * mul;
  } else if (tid < 896){
    int o = tid - 768;
    for (int c = 0; c < 128; ++c) pw[o * 128 + c] = f2bf(proj_w[o * 128 + c]);
  }
}

// ---------------- K2: QKV GEMM -> Qt[b][s][128], KVt[b][s][256]
// 1728 blocks x 128thr (3456 waves); wave does 3 of 12 output tiles for a 32-s tile.
__global__ __launch_bounds__(128) void k_qkv(const float* __restrict__ x, const ushort* __restrict__ Wp,
                                             const float* __restrict__ biasP,
                                             ushort* __restrict__ Qt, ushort* __restrict__ KVt){
  int bid = blockIdx.x;                 // 1728 = b*864 + st2*2 + half
  int half = bid & 1;
  int st2 = (bid >> 1) % 432;
  int b  = bid / 864;
  int t = threadIdx.x, w = t >> 6, lane = t & 63, hl = lane >> 5, ln = lane & 31;
  int s0 = st2 * 32;
  int s = s0 + ln;
  const float* xb = x + (size_t)b * 128 * SS;
  // A fragments: rows = s (lane&31), k = c; 64 coalesced dword gathers, packed converts
  bf16x8 afr[8];
  #pragma unroll
  for (int ks = 0; ks < 8; ++ks){
    int cb = ks * 16 + hl * 8;
    float xv[8];
    #pragma unroll
    for (int j = 0; j < 8; ++j)
      xv[j] = xb[(size_t)(cb + j) * SS + s];
    union { uint u[4]; bf16x8 b8; } f;
    #pragma unroll
    for (int j2 = 0; j2 < 4; ++j2) f.u[j2] = pk2(xv[2 * j2], xv[2 * j2 + 1]);
    afr[ks] = f.b8;
  }
  int tb = half * 6 + w * 3;
  for (int oi = 0; oi < 3; ++oi){
    int o0 = (tb + oi) * 32;
    f32x16 acc = {};
    const ushort* wrow = Wp + (size_t)(b * 384 + o0 + ln) * 128 + hl * 8;
    #pragma unroll
    for (int ks = 0; ks < 8; ++ks)
      acc = mfma32(afr[ks], ldg8(wrow + ks * 16), acc);
    float bo = biasP[b * 384 + o0 + ln];
    if (o0 < 128){
      #pragma unroll
      for (int r = 0; r < 16; r += 2){
        int srow = s0 + rowmap(r, hl);           // rowmap(r+1) = rowmap(r)+1 for even r
        uint pr = pk2(acc[r] + bo, acc[r + 1] + bo);
        Qt[(size_t)(b * SS + srow) * 128 + o0 + ln] = (ushort)pr;
        Qt[(size_t)(b * SS + srow + 1) * 128 + o0 + ln] = (ushort)(pr >> 16);
      }
    } else {
      #pragma unroll
      for (int r = 0; r < 16; r += 2){
        int srow = s0 + rowmap(r, hl);
        uint pr = pk2(acc[r] + bo, acc[r + 1] + bo);
        KVt[(size_t)(b * SS + srow) * 256 + (o0 - 128) + ln] = (ushort)pr;
        KVt[(size_t)(b * SS + srow + 1) * 256 + (o0 - 128) + ln] = (ushort)(pr >> 16);
      }
    }
  }
}

// ---------------- K3: 2x2x2 avg-pool -> fragment-linear kfr/vfr. CONTIGUOUS reads:
// each pooled key's 8 source rows read as 4 x 1KB row-pair loads (kk via lane half,
// summed with one shfl_xor). 54 blocks x 256 thr; K/V staged in LDS, then
// fragment-linear writes (mapping identical to R3 spec, re-verified). ----------------
__global__ __launch_bounds__(256) void k_pool(const ushort* __restrict__ KVt,
                                              ushort* __restrict__ kfr, ushort* __restrict__ vfr){
  int bid = blockIdx.x;          // 54 = b*27 + mt
  int mt = bid % 27;
  int b  = bid / 27;
  int m0 = mt * 64;
  int t = threadIdx.x, w = t >> 6, lane = t & 63, hl = lane >> 5, ln = lane & 31;
  __shared__ ushort K_lds[64][136];  // [key-local][K channel 0..127], pitch 272B
  __shared__ ushort V_lds[64][136];  // [key-local][V channel 0..127]
  const ushort* kvb = KVt + (size_t)b * SS * 256;
  // phase 1: pooled sums; wave w owns keys w*16..w*16+15
  for (int mi = 0; mi < 16; ++mi){
    int ml = w * 16 + mi;
    int m = m0 + ml;
    int h2 = m / 144; int rem = m - h2 * 144; int w2 = rem / 12; int d2 = rem - w2 * 12;
    int sb = h2 * 1152 + w2 * 48 + d2 * 2 + hl;   // hl = kk (adjacent row in pair)
    float acc[8] = {0,0,0,0,0,0,0,0};
    #pragma unroll
    for (int i = 0; i < 2; ++i)
      #pragma unroll
      for (int jj = 0; jj < 2; ++jj){
        const ushort* row = kvb + (size_t)(sb + i * 576 + jj * 24) * 256 + ln * 8;
        union { uint4 q; ushort us[8]; } u;
        u.q = *reinterpret_cast<const uint4*>(row);   // 64 lanes x 16B = row-pair, contiguous 1KB
        #pragma unroll
        for (int j = 0; j < 8; ++j) acc[j] += bf2f(u.us[j]);
      }
    #pragma unroll
    for (int j = 0; j < 8; ++j) acc[j] += __shfl_xor(acc[j], 32, 64);
    if (hl == 0){
      union { uint u[4]; uint4 q; } pk;
      #pragma unroll
      for (int j2 = 0; j2 < 4; ++j2)
        pk.u[j2] = pk2(acc[2 * j2] * 0.125f, acc[2 * j2 + 1] * 0.125f);
      if (ln < 16) *reinterpret_cast<uint4*>(&K_lds[ml][ln * 8]) = pk.q;          // ch 0..127 = K
      else         *reinterpret_cast<uint4*>(&V_lds[ml][(ln - 16) * 8]) = pk.q;   // ch 128..255 = V
    }
  }
  __syncthreads();
  // phase 2a: K fragment-linear writes (thread = (kl, o), loop heads)
  int kl = t & 63, o = t >> 6;
  #pragma unroll
  for (int h = 0; h < 4; ++h){
    uint4 kk_ = *reinterpret_cast<const uint4*>(&K_lds[kl][h * 32 + o * 8]);
    int call = 2 * (kl >> 5) + (o >> 1);
    int lane2 = (kl & 31) + 32 * (o & 1);
    size_t kb_ = ((size_t)((b * 4 + h) * 27 + mt) * 4 + call) * 512 + lane2 * 8;
    *reinterpret_cast<uint4*>(&kfr[kb_]) = kk_;
  }
  // phase 2b: V transposed fragment-linear writes (thread = (d, key-octet))
  int d = t & 31, ko = t >> 5;
  int c = ko >> 1, hl2 = ko & 1;
  #pragma unroll
  for (int h = 0; h < 4; ++h){
    union { ushort us[8]; uint4 q; } vv;
    #pragma unroll
    for (int j = 0; j < 8; ++j)
      vv.us[j] = V_lds[c * 16 + hl2 * 8 + j][h * 32 + d];
    size_t vb_ = ((size_t)((b * 4 + h) * 27 + mt) * 4 + c) * 512 + (d + 32 * hl2) * 8;
    *reinterpret_cast<uint4*>(&vfr[vb_]) = vv.q;
  }
}

// ---------------- K4: FUSED attention + proj (R12, unchanged). ----------------
#define PVSTEP(Parr, i4, vf, oac)                                    \
  {                                                                  \
    uint a0 = Parr[(i4) + 0], a1 = Parr[(i4) + 1];                   \
    uint b0 = Parr[(i4) + 2], b1 = Parr[(i4) + 3];                   \
    asm("v_permlane32_swap_b32 %0, %1" : "+v"(a0), "+v"(b0));        \
    asm("v_permlane32_swap_b32 %0, %1" : "+v"(a1), "+v"(b1));        \
    union { uint u[4]; bf16x8 b8; } pf;                              \
    pf.u[0] = a0; pf.u[1] = a1; pf.u[2] = b0; pf.u[3] = b1;          \
    oac = mfma32(vf, pf.b8, oac);                                    \
    lacc = mfma32(ones, pf.b8, lacc);                                \
  }

__global__ __launch_bounds__(256, 2) void k_attn(const ushort* __restrict__ Qt, const ushort* __restrict__ kfr,
                                                 const ushort* __restrict__ vfr, const ushort* __restrict__ pw,
                                                 const float* __restrict__ pb, const float* __restrict__ xres,
                                                 float* __restrict__ out){
  int bid = blockIdx.x;           // 864 = b*432 + qt
  int qt = bid % 432;
  int b  = bid / 432;
  int t = threadIdx.x, w = t >> 6, lane = t & 63, hl = lane >> 5, ln = lane & 31;
  int n = qt * 32 + ln;           // query row (32 q per block, shared by all 4 waves)
  int h = w;                      // wave = head
  int bh = b * 4 + h;
  const ushort* qrow = Qt + (size_t)(b * SS + n) * 128 + h * 32;
  bf16x8 qf0 = ldg8(qrow + hl * 8);
  bf16x8 qf1 = ldg8(qrow + 16 + hl * 8);
  const ushort* kbase = kfr + (size_t)bh * 27 * 2048 + (size_t)lane * 8;
  const ushort* vbase = vfr + (size_t)bh * 27 * 2048 + (size_t)lane * 8;
  union { ushort us[8]; bf16x8 b8; } one8;
  #pragma unroll
  for (int j = 0; j < 8; ++j) one8.us[j] = 0x3F80; // bf16 1.0
  bf16x8 ones = one8.b8;
  const f32x16 fz = {};           // persistent zero block for MFMA C-operands
  f32x16 oA = fz, oB = fz, lacc = fz;
  // preload K tile 0
  bf16x8 kc0 = ldg8(kbase), kc1 = ldg8(kbase + 512);
  bf16x8 kc2 = ldg8(kbase + 1024), kc3 = ldg8(kbase + 1536);
  for (int it = 0; it < 27; ++it){
    const ushort* vp = vbase + it * 2048;
    bf16x8 v0 = ldg8(vp), v1 = ldg8(vp + 512), v2 = ldg8(vp + 1024), v3 = ldg8(vp + 1536);
    int itn = it + 1; if (itn == 27) itn = 0;  // wrap: keep addresses valid
    const ushort* kpn = kbase + itn * 2048;
    bf16x8 kn0 = ldg8(kpn), kn1 = ldg8(kpn + 512);
    bf16x8 kn2 = ldg8(kpn + 1024), kn3 = ldg8(kpn + 1536);
    // QK^T on current K (loaded a full iteration ago)
    f32x16 s0 = mfma32(kc0, qf0, fz);
    s0 = mfma32(kc1, qf1, s0);
    f32x16 s1 = mfma32(kc2, qf0, fz);
    s1 = mfma32(kc3, qf1, s1);
    // stateless softmax numerator: P = exp2(s), single TRANS instruction each
    #pragma unroll
    for (int r = 0; r < 16; ++r) s0[r] = vexp2(s0[r]);
    #pragma unroll
    for (int r = 0; r < 16; ++r) s1[r] = vexp2(s1[r]);
    uint P0[8], P1[8];
    #pragma unroll
    for (int i = 0; i < 8; ++i) P0[i] = pk2(s0[2 * i], s0[2 * i + 1]);
    #pragma unroll
    for (int i = 0; i < 8; ++i) P1[i] = pk2(s1[2 * i], s1[2 * i + 1]);
    PVSTEP(P0, 0, v0, oA)
    PVSTEP(P0, 4, v1, oB)
    PVSTEP(P1, 0, v2, oA)
    PVSTEP(P1, 4, v3, oB)
    kc0 = kn0; kc1 = kn1; kc2 = kn2; kc3 = kn3;
  }
  float inv = 1.f / lacc[0];      // lacc rows all hold sum_k P[k][col]
  // O tile in LDS: [query][channel], pitch 136 ushorts (272B, 16B-aligned rows)
  __shared__ ushort OT[32][136];
  #pragma unroll
  for (int r = 0; r < 16; r += 2){
    int d = rowmap(r, hl);        // even; rowmap(r+1) = d+1
    uint pr = pk2((oA[r] + oB[r]) * inv, (oA[r + 1] + oB[r + 1]) * inv);
    *reinterpret_cast<uint*>(&OT[ln][h * 32 + d]) = pr;
  }
  __syncthreads();
  // proj phase: wave w computes output rows ot=w (32 o-rows) for all 32 queries
  bf16x8 bfr[8];
  #pragma unroll
  for (int ks = 0; ks < 8; ++ks)
    bfr[ks] = ldg8(&OT[ln][ks * 16 + hl * 8]);
  f32x16 acc = fz;
  const ushort* arow = pw + (size_t)(w * 32 + ln) * 128 + hl * 8;
  #pragma unroll
  for (int ks = 0; ks < 8; ++ks)
    acc = mfma32(ldg8(arow + ks * 16), bfr[ks], acc);
  #pragma unroll
  for (int r = 0; r < 16; ++r){
    int o = w * 32 + rowmap(r, hl);
    size_t idx = (size_t)(b * 128 + o) * SS + n;
    out[idx] = acc[r] + pb[o] + xres[idx];
  }
}

extern "C" void kernel_launch(void* const* d_in, const int* in_sizes, int n_in,
                              void* d_out, int out_size, void* d_ws, size_t ws_size,
                              hipStream_t stream){
  const float* x      = (const float*)d_in[0];
  const float* gn_w   = (const float*)d_in[1];
  const float* gn_b   = (const float*)d_in[2];
  const float* qkv_w  = (const float*)d_in[3];
  const float* qkv_b  = (const float*)d_in[4];
  const float* proj_w = (const float*)d_in[5];
  const float* proj_b = (const float*)d_in[6];
  float* out = (float*)d_out;
  char* ws = (char*)d_ws;

  float*  chsums = (float*) (ws + 0);          // 2048 B
  ushort* Wp     = (ushort*)(ws + 2048);       // 196608 B
  float*  biasP  = (float*) (ws + 198656);     // 3072 B
  ushort* pw     = (ushort*)(ws + 201728);     // 32768 B
  ushort* Qt     = (ushort*)(ws + 234496);     // 7077888 B  [b][s][128]
  ushort* KVt    = (ushort*)(ws + 7312384);    // 14155776 B [b][s][256]
  ushort* kfr    = (ushort*)(ws + 21468160);   // 884736 B (fragment-linear K)
  ushort* vfr    = (ushort*)(ws + 22352896);   // 884736 B (fragment-linear V)

  k_stats <<<256,  256, 0, stream>>>(x, chsums);
  k_params<<<4,    256, 0, stream>>>(chsums, gn_w, gn_b, qkv_w, qkv_b, proj_w, Wp, biasP, pw);
  k_qkv   <<<1728, 128, 0, stream>>>(x, Wp, biasP, Qt, KVt);
  k_pool  <<<54,   256, 0, stream>>>(KVt, kfr, vfr);
  k_attn  <<<864,  256, 0, stream>>>(Qt, kfr, vfr, pw, proj_b, x, out);
}

// Round 14
// 94.878 us; speedup vs baseline: 1.0836x; 1.0836x over previous
//
#include <hip/hip_runtime.h>
#include <hip/hip_bf16.h>

// Problem constants: B=2, C=128, H=W=D=24, S=13824, NH=4, hd=32, pooled SKV=1728, G=8
#define SB 2
#define SC 128
#define SS 13824
#define SNH 4
#define SHD 32
#define SKV 1728
#define GN_N 221184.0f        // elems per (b,g) = 16*13824
#define QSCALE 0.25504771249f // (1/sqrt(32)) * log2(e)

typedef unsigned int uint;
typedef unsigned short ushort;
typedef __bf16 bf16x8 __attribute__((ext_vector_type(8)));
typedef float f32x16 __attribute__((ext_vector_type(16)));

__device__ inline ushort f2bf(float v){
  __hip_bfloat16 h = __float2bfloat16(v);
  return *reinterpret_cast<ushort*>(&h);
}
__device__ inline float bf2f(ushort u){
  union { ushort s[2]; float f; } x; x.s[0] = 0; x.s[1] = u; return x.f;
}
__device__ inline uint pk2(float a, float b){
  __hip_bfloat162 h = __float22bfloat162_rn(make_float2(a, b));
  return *reinterpret_cast<uint*>(&h);
}
__device__ inline bf16x8 ldg8(const ushort* p){
  union { uint4 q; bf16x8 b; } u;
  u.q = *reinterpret_cast<const uint4*>(p);
  return u.b;
}
__device__ inline f32x16 mfma32(bf16x8 a, bf16x8 b, f32x16 c){
  return __builtin_amdgcn_mfma_f32_32x32x16_bf16(a, b, c, 0, 0, 0);
}
// C/D layout of 32x32 MFMA: col = lane&31, row = (r&3) + 8*((r>>2)&1) + 4*(lane>>5) + 16*(r>>3)
__device__ inline int rowmap(int r, int hl){
  return (r & 3) + 8 * ((r >> 2) & 1) + 4 * hl + 16 * (r >> 3);
}
// RAW v_exp_f32: guaranteed single TRANS-pipe instruction.
// Safe domain here: |scores| < ~40, so no denormal/inf handling needed.
__device__ inline float vexp2(float x){
  float r;
  asm("v_exp_f32 %0, %1" : "=v"(r) : "v"(x));
  return r;
}

// ---------------- K1a: per-channel sums for GroupNorm stats ----------------
__global__ __launch_bounds__(256) void k_stats(const float* __restrict__ x, float* __restrict__ chsums){
  int bid = blockIdx.x;            // 256 blocks = (b, c)
  int b = bid >> 7, c = bid & 127;
  const float4* p = reinterpret_cast<const float4*>(x + (size_t)(b * 128 + c) * SS);
  float s = 0.f, q = 0.f;
  for (int i = threadIdx.x; i < SS / 4; i += 256){
    float4 v = p[i];
    s += v.x + v.y + v.z + v.w;
    q += v.x * v.x + v.y * v.y + v.z * v.z + v.w * v.w;
  }
  for (int off = 32; off; off >>= 1){ s += __shfl_down(s, off, 64); q += __shfl_down(q, off, 64); }
  __shared__ float ls[4][2];
  int w = threadIdx.x >> 6, lane = threadIdx.x & 63;
  if (lane == 0){ ls[w][0] = s; ls[w][1] = q; }
  __syncthreads();
  if (threadIdx.x == 0){
    float S = ls[0][0] + ls[1][0] + ls[2][0] + ls[3][0];
    float Q = ls[0][1] + ls[1][1] + ls[2][1] + ls[3][1];
    chsums[(b * 128 + c) * 2] = S;
    chsums[(b * 128 + c) * 2 + 1] = Q;
  }
}

// ---------------- K1b: fold GN into qkv weights; convert proj_w ----------------
__global__ __launch_bounds__(256) void k_params(const float* __restrict__ chsums,
                                                const float* __restrict__ gn_w, const float* __restrict__ gn_b,
                                                const float* __restrict__ qkv_w, const float* __restrict__ qkv_b,
                                                const float* __restrict__ proj_w,
                                                ushort* __restrict__ Wp, float* __restrict__ biasP,
                                                ushort* __restrict__ pw){
  int tid = blockIdx.x * 256 + threadIdx.x;
  if (tid < 768){
    int b = tid / 384, o = tid % 384;
    float mul = (o < 128) ? QSCALE : 1.0f; // fold softmax scale*log2e into q
    ushort* wrow = Wp + (size_t)(b * 384 + o) * 128;
    float acc = 0.f;
    for (int g = 0; g < 8; ++g){
      float S = 0.f, Q = 0.f;
      for (int ch = g * 16; ch < g * 16 + 16; ++ch){
        S += chsums[(b * 128 + ch) * 2];
        Q += chsums[(b * 128 + ch) * 2 + 1];
      }
      float mu = S * (1.0f / GN_N);
      float var = Q * (1.0f / GN_N) - mu * mu;
      float rs = rsqrtf(var + 1e-5f);
      for (int ci = 0; ci < 16; ++ci){
        int c = g * 16 + ci;
        float a = gn_w[c] * rs;
        float be = gn_b[c] - mu * a;
        float wv = qkv_w[o * 128 + c];
        acc += wv * be;
        wrow[c] = f2bf(wv * a * mul);
      }
    }
    biasP[b * 384 + o] = (qkv_b[o] + acc) * mul;
  } else if (tid < 896){
    int o = tid - 768;
    for (int c = 0; c < 128; ++c) pw[o * 128 + c] = f2bf(proj_w[o * 128 + c]);
  }
}

// ---------------- K2: QKV GEMM -> Qt[b][s][128], KVt[b][s][256]
// 864 blocks x 128thr (R12 grid). x tile staged via LDS: 8 coalesced loads/thread
// (8x128B segments each) replace the old 64 scattered dword gathers; A-fragments
// then come from 8 ds_read_b128. Wave pair splits 12 output tiles 6/6.
__global__ __launch_bounds__(128) void k_qkv(const float* __restrict__ x, const ushort* __restrict__ Wp,
                                             const float* __restrict__ biasP,
                                             ushort* __restrict__ Qt, ushort* __restrict__ KVt){
  int bid = blockIdx.x;                 // 864 = b*432 + st2
  int st2 = bid % 432;
  int b  = bid / 432;
  int t = threadIdx.x, w = t >> 6, lane = t & 63, hl = lane >> 5, ln = lane & 31;
  int s0 = st2 * 32;
  const float* xb = x + (size_t)b * 128 * SS + s0;
  __shared__ ushort XT[32][136];        // [s_local][channel], pitch 272B (16B-aligned rows)
  // phase 1: coalesced x tile load -> bf16 -> LDS transpose
  #pragma unroll
  for (int j = 0; j < 8; ++j){
    int c = w * 64 + j * 8 + (lane >> 3);   // wave covers 8 channel rows per instr
    int f4 = lane & 7;                      // float4 slot within the 32-query row
    float4 v = *reinterpret_cast<const float4*>(xb + (size_t)c * SS + f4 * 4);
    uint p0 = pk2(v.x, v.y), p1 = pk2(v.z, v.w);
    int sl = f4 * 4;
    XT[sl + 0][c] = (ushort)p0;
    XT[sl + 1][c] = (ushort)(p0 >> 16);
    XT[sl + 2][c] = (ushort)p1;
    XT[sl + 3][c] = (ushort)(p1 >> 16);
  }
  __syncthreads();
  // phase 2: A fragments from LDS (one ds_read_b128 each)
  bf16x8 afr[8];
  #pragma unroll
  for (int ks = 0; ks < 8; ++ks)
    afr[ks] = ldg8(&XT[ln][ks * 16 + hl * 8]);
  for (int oi = 0; oi < 6; ++oi){
    int o0 = (w * 6 + oi) * 32;
    f32x16 acc = {};
    const ushort* wrow = Wp + (size_t)(b * 384 + o0 + ln) * 128 + hl * 8;
    #pragma unroll
    for (int ks = 0; ks < 8; ++ks)
      acc = mfma32(afr[ks], ldg8(wrow + ks * 16), acc);
    float bo = biasP[b * 384 + o0 + ln];
    if (o0 < 128){
      #pragma unroll
      for (int r = 0; r < 16; r += 2){
        int srow = s0 + rowmap(r, hl);           // rowmap(r+1) = rowmap(r)+1 for even r
        uint pr = pk2(acc[r] + bo, acc[r + 1] + bo);
        Qt[(size_t)(b * SS + srow) * 128 + o0 + ln] = (ushort)pr;
        Qt[(size_t)(b * SS + srow + 1) * 128 + o0 + ln] = (ushort)(pr >> 16);
      }
    } else {
      #pragma unroll
      for (int r = 0; r < 16; r += 2){
        int srow = s0 + rowmap(r, hl);
        uint pr = pk2(acc[r] + bo, acc[r + 1] + bo);
        KVt[(size_t)(b * SS + srow) * 256 + (o0 - 128) + ln] = (ushort)pr;
        KVt[(size_t)(b * SS + srow + 1) * 256 + (o0 - 128) + ln] = (ushort)(pr >> 16);
      }
    }
  }
}

// ---------------- K3: 2x2x2 avg-pool of K,V -> MFMA-fragment-linear layout (R12 version) ----------------
__global__ __launch_bounds__(256) void k_pool(const ushort* __restrict__ KVt,
                                              ushort* __restrict__ kfr, ushort* __restrict__ vfr){
  int bid = blockIdx.x;          // 216 = b*108 + h*27 + mt
  int mt = bid % 27;
  int h  = (bid / 27) & 3;
  int b  = bid / 108;
  int m0 = mt * 64;
  int t = threadIdx.x;
  int kl = t & 63, o = t >> 6;   // key-local 0..63, d-octet 0..3
  int m = m0 + kl;
  int h2 = m / 144; int rem = m - h2 * 144; int w2 = rem / 12; int d2 = rem - w2 * 12;
  int sb = h2 * 1152 + w2 * 48 + d2 * 2;
  const ushort* base = KVt + (size_t)b * SS * 256 + h * 32 + o * 8;
  float ks[8] = {0,0,0,0,0,0,0,0}, vs[8] = {0,0,0,0,0,0,0,0};
  #pragma unroll
  for (int i = 0; i < 2; ++i)
    #pragma unroll
    for (int jj = 0; jj < 2; ++jj)
      #pragma unroll
      for (int kk = 0; kk < 2; ++kk){
        const ushort* row = base + (size_t)(sb + i * 576 + jj * 24 + kk) * 256;
        union { uint4 q; ushort us[8]; } K8, V8;
        K8.q = *reinterpret_cast<const uint4*>(row);        // K chunk (cols 0..127)
        V8.q = *reinterpret_cast<const uint4*>(row + 128);  // V chunk (cols 128..255)
        #pragma unroll
        for (int j = 0; j < 8; ++j){ ks[j] += bf2f(K8.us[j]); vs[j] += bf2f(V8.us[j]); }
      }
  union { uint u[4]; uint4 q; } KW;
  #pragma unroll
  for (int j2 = 0; j2 < 4; ++j2)
    KW.u[j2] = pk2(ks[2 * j2] * 0.125f, ks[2 * j2 + 1] * 0.125f);
  int call = 2 * (kl >> 5) + (o >> 1);
  int lane = (kl & 31) + 32 * (o & 1);
  size_t kb_ = ((size_t)((b * 4 + h) * 27 + mt) * 4 + call) * 512 + lane * 8;
  *reinterpret_cast<uint4*>(&kfr[kb_]) = KW.q;
  __shared__ ushort V_lds[32][72];
  #pragma unroll
  for (int j2 = 0; j2 < 4; ++j2){
    uint pv = pk2(vs[2 * j2] * 0.125f, vs[2 * j2 + 1] * 0.125f);
    V_lds[o * 8 + 2 * j2][kl] = (ushort)pv;
    V_lds[o * 8 + 2 * j2 + 1][kl] = (ushort)(pv >> 16);
  }
  __syncthreads();
  int d = t & 31, ko = t >> 5;   // d 0..31, key-octet 0..7
  uint4 vv = *reinterpret_cast<const uint4*>(&V_lds[d][ko * 8]);
  int c = ko >> 1, hl2 = ko & 1;
  int lane2 = d + 32 * hl2;
  size_t vb_ = ((size_t)((b * 4 + h) * 27 + mt) * 4 + c) * 512 + lane2 * 8;
  *reinterpret_cast<uint4*>(&vfr[vb_]) = vv;
}

// ---------------- K4: FUSED attention + proj (R12, unchanged). ----------------
#define PVSTEP(Parr, i4, vf, oac)                                    \
  {                                                                  \
    uint a0 = Parr[(i4) + 0], a1 = Parr[(i4) + 1];                   \
    uint b0 = Parr[(i4) + 2], b1 = Parr[(i4) + 3];                   \
    asm("v_permlane32_swap_b32 %0, %1" : "+v"(a0), "+v"(b0));        \
    asm("v_permlane32_swap_b32 %0, %1" : "+v"(a1), "+v"(b1));        \
    union { uint u[4]; bf16x8 b8; } pf;                              \
    pf.u[0] = a0; pf.u[1] = a1; pf.u[2] = b0; pf.u[3] = b1;          \
    oac = mfma32(vf, pf.b8, oac);                                    \
    lacc = mfma32(ones, pf.b8, lacc);                                \
  }

__global__ __launch_bounds__(256, 2) void k_attn(const ushort* __restrict__ Qt, const ushort* __restrict__ kfr,
                                                 const ushort* __restrict__ vfr, const ushort* __restrict__ pw,
                                                 const float* __restrict__ pb, const float* __restrict__ xres,
                                                 float* __restrict__ out){
  int bid = blockIdx.x;           // 864 = b*432 + qt
  int qt = bid % 432;
  int b  = bid / 432;
  int t = threadIdx.x, w = t >> 6, lane = t & 63, hl = lane >> 5, ln = lane & 31;
  int n = qt * 32 + ln;           // query row (32 q per block, shared by all 4 waves)
  int h = w;                      // wave = head
  int bh = b * 4 + h;
  const ushort* qrow = Qt + (size_t)(b * SS + n) * 128 + h * 32;
  bf16x8 qf0 = ldg8(qrow + hl * 8);
  bf16x8 qf1 = ldg8(qrow + 16 + hl * 8);
  const ushort* kbase = kfr + (size_t)bh * 27 * 2048 + (size_t)lane * 8;
  const ushort* vbase = vfr + (size_t)bh * 27 * 2048 + (size_t)lane * 8;
  union { ushort us[8]; bf16x8 b8; } one8;
  #pragma unroll
  for (int j = 0; j < 8; ++j) one8.us[j] = 0x3F80; // bf16 1.0
  bf16x8 ones = one8.b8;
  const f32x16 fz = {};           // persistent zero block for MFMA C-operands
  f32x16 oA = fz, oB = fz, lacc = fz;
  // preload K tile 0
  bf16x8 kc0 = ldg8(kbase), kc1 = ldg8(kbase + 512);
  bf16x8 kc2 = ldg8(kbase + 1024), kc3 = ldg8(kbase + 1536);
  for (int it = 0; it < 27; ++it){
    const ushort* vp = vbase + it * 2048;
    bf16x8 v0 = ldg8(vp), v1 = ldg8(vp + 512), v2 = ldg8(vp + 1024), v3 = ldg8(vp + 1536);
    int itn = it + 1; if (itn == 27) itn = 0;  // wrap: keep addresses valid
    const ushort* kpn = kbase + itn * 2048;
    bf16x8 kn0 = ldg8(kpn), kn1 = ldg8(kpn + 512);
    bf16x8 kn2 = ldg8(kpn + 1024), kn3 = ldg8(kpn + 1536);
    // QK^T on current K (loaded a full iteration ago)
    f32x16 s0 = mfma32(kc0, qf0, fz);
    s0 = mfma32(kc1, qf1, s0);
    f32x16 s1 = mfma32(kc2, qf0, fz);
    s1 = mfma32(kc3, qf1, s1);
    // stateless softmax numerator: P = exp2(s), single TRANS instruction each
    #pragma unroll
    for (int r = 0; r < 16; ++r) s0[r] = vexp2(s0[r]);
    #pragma unroll
    for (int r = 0; r < 16; ++r) s1[r] = vexp2(s1[r]);
    uint P0[8], P1[8];
    #pragma unroll
    for (int i = 0; i < 8; ++i) P0[i] = pk2(s0[2 * i], s0[2 * i + 1]);
    #pragma unroll
    for (int i = 0; i < 8; ++i) P1[i] = pk2(s1[2 * i], s1[2 * i + 1]);
    PVSTEP(P0, 0, v0, oA)
    PVSTEP(P0, 4, v1, oB)
    PVSTEP(P1, 0, v2, oA)
    PVSTEP(P1, 4, v3, oB)
    kc0 = kn0; kc1 = kn1; kc2 = kn2; kc3 = kn3;
  }
  float inv = 1.f / lacc[0];      // lacc rows all hold sum_k P[k][col]
  // O tile in LDS: [query][channel], pitch 136 ushorts (272B, 16B-aligned rows)
  __shared__ ushort OT[32][136];
  #pragma unroll
  for (int r = 0; r < 16; r += 2){
    int d = rowmap(r, hl);        // even; rowmap(r+1) = d+1
    uint pr = pk2((oA[r] + oB[r]) * inv, (oA[r + 1] + oB[r + 1]) * inv);
    *reinterpret_cast<uint*>(&OT[ln][h * 32 + d]) = pr;
  }
  __syncthreads();
  // proj phase: wave w computes output rows ot=w (32 o-rows) for all 32 queries
  bf16x8 bfr[8];
  #pragma unroll
  for (int ks = 0; ks < 8; ++ks)
    bfr[ks] = ldg8(&OT[ln][ks * 16 + hl * 8]);
  f32x16 acc = fz;
  const ushort* arow = pw + (size_t)(w * 32 + ln) * 128 + hl * 8;
  #pragma unroll
  for (int ks = 0; ks < 8; ++ks)
    acc = mfma32(ldg8(arow + ks * 16), bfr[ks], acc);
  #pragma unroll
  for (int r = 0; r < 16; ++r){
    int o = w * 32 + rowmap(r, hl);
    size_t idx = (size_t)(b * 128 + o) * SS + n;
    out[idx] = acc[r] + pb[o] + xres[idx];
  }
}

extern "C" void kernel_launch(void* const* d_in, const int* in_sizes, int n_in,
                              void* d_out, int out_size, void* d_ws, size_t ws_size,
                              hipStream_t stream){
  const float* x      = (const float*)d_in[0];
  const float* gn_w   = (const float*)d_in[1];
  const float* gn_b   = (const float*)d_in[2];
  const float* qkv_w  = (const float*)d_in[3];
  const float* qkv_b  = (const float*)d_in[4];
  const float* proj_w = (const float*)d_in[5];
  const float* proj_b = (const float*)d_in[6];
  float* out = (float*)d_out;
  char* ws = (char*)d_ws;

  float*  chsums = (float*) (ws + 0);          // 2048 B
  ushort* Wp     = (ushort*)(ws + 2048);       // 196608 B
  float*  biasP  = (float*) (ws + 198656);     // 3072 B
  ushort* pw     = (ushort*)(ws + 201728);     // 32768 B
  ushort* Qt     = (ushort*)(ws + 234496);     // 7077888 B  [b][s][128]
  ushort* KVt    = (ushort*)(ws + 7312384);    // 14155776 B [b][s][256]
  ushort* kfr    = (ushort*)(ws + 21468160);   // 884736 B (fragment-linear K)
  ushort* vfr    = (ushort*)(ws + 22352896);   // 884736 B (fragment-linear V)

  k_stats <<<256, 256, 0, stream>>>(x, chsums);
  k_params<<<4,   256, 0, stream>>>(chsums, gn_w, gn_b, qkv_w, qkv_b, proj_w, Wp, biasP, pw);
  k_qkv   <<<864, 128, 0, stream>>>(x, Wp, biasP, Qt, KVt);
  k_pool  <<<216, 256, 0, stream>>>(KVt, kfr, vfr);
  k_attn  <<<864, 256, 0, stream>>>(Qt, kfr, vfr, pw, proj_b, x, out);
}